// Round 2
// baseline (400.938 us; speedup 1.0000x reference)
//
#include <hip/hip_runtime.h>

// AttnInteractionLayer reduces algebraically to:
//   out = LN(ReLU(x @ (m*W_v + (1-m)*W_r))) * gamma + beta,  m = sigmoid(mix[0])
// (softmax summed over its own axis == 1 -> attention pair is vals-identity; W_q,W_k dead.)
// Kernel 1: pack W_mix -> bf16 in MFMA B-fragment order (256 KiB in d_ws).
// Kernel 2: fused GEMM (bf16 MFMA, fp32 acc) + ReLU + LayerNorm + LDS-transposed
//           coalesced nontemporal float4 stores.

#define ROWS_TOT 131072   // 2048*64
#define K_DIM 256
#define N_DIM 512
#define BM 32
#define LDA 260           // padded fp32 row stride for A in LDS
#define LDO 516           // padded fp32 row stride for out-tile in LDS (516%32=4 -> 2-way max)

typedef float f32x4 __attribute__((ext_vector_type(4)));
typedef short s16x8 __attribute__((ext_vector_type(8)));

__device__ __forceinline__ unsigned f2bf(float f) {
  unsigned u = __builtin_bit_cast(unsigned, f);
  u += 0x7FFFu + ((u >> 16) & 1u);   // round-to-nearest-even
  return u >> 16;
}

// ---- Kernel 1: W_mix = m*W_v + (1-m)*W_r, packed per 16x16x32 B-fragment layout:
//   B[k][n] -> tile (ks=k/32, nt=n/16), lane = (k%32/8)*16 + n%16, j = k%8
__global__ void prep_wmix(const float* __restrict__ Wv, const float* __restrict__ Wr,
                          const float* __restrict__ mix, unsigned short* __restrict__ Bp) {
  int idx = blockIdx.x * 256 + threadIdx.x;   // 0..131071 ; idx = k*512 + n
  float m = 1.f / (1.f + __expf(-mix[0]));
  float val = m * Wv[idx] + (1.f - m) * Wr[idx];
  int k = idx >> 9, n = idx & 511;
  int ks = k >> 5, kin = k & 31, nt = n >> 4, nin = n & 15;
  int lane = ((kin >> 3) << 4) | nin;
  int j = kin & 7;
  Bp[((ks * 32 + nt) * 64 + lane) * 8 + j] = (unsigned short)f2bf(val);
}

// ---- Kernel 2: per block: 32 rows x 512 cols. 8 waves; wave w owns cols [64w,64w+64).
__global__ __launch_bounds__(512, 4) void gemm_ln(
    const float* __restrict__ x, const unsigned short* __restrict__ Bp,
    const float* __restrict__ gamma, const float* __restrict__ beta,
    float* __restrict__ out) {
  // A-tile (33.3 KiB) and out-tile (66 KiB) are live in disjoint phases -> union.
  __shared__ char smem[BM * LDO * 4];          // 66048 B
  float* As = (float*)smem;                    // [BM][LDA] fp32, K=256 fully resident
  float* Os = (float*)smem;                    // [BM][LDO] fp32 out staging
  __shared__ float redS[8 * BM];
  __shared__ float redQ[8 * BM];
  __shared__ float statM[BM];
  __shared__ float statR[BM];

  const int tid  = threadIdx.x;
  const int w    = tid >> 6;
  const int lane = tid & 63;
  const int q    = lane >> 4;
  const int l15  = lane & 15;
  const long rowbase = (long)blockIdx.x * BM;

  // stage A via async global->LDS DMA: one full row (1 KiB, 64 lanes x 16 B) per instr
  #pragma unroll
  for (int i = 0; i < 4; ++i) {
    int r = i * 8 + w;
    const float* gsrc = x + (rowbase + r) * K_DIM + lane * 4;
    __builtin_amdgcn_global_load_lds(
        (const __attribute__((address_space(1))) unsigned int*)gsrc,
        (__attribute__((address_space(3))) unsigned int*)(&As[r * LDA]),
        16, 0, 0);
  }

  float gv[4], bv[4];
  #pragma unroll
  for (int nt = 0; nt < 4; ++nt) {
    int col = w * 64 + nt * 16 + l15;
    gv[nt] = gamma[col];
    bv[nt] = beta[col];
  }

  __syncthreads();   // drains LDS-DMA (compiler emits vmcnt(0) before s_barrier)

  f32x4 acc[2][4] = {};
  const uint4* Bp4 = (const uint4*)Bp;

  // barrier-free K-loop: 8 K-steps of 32; unroll 4 caps live B-frags (VGPR<=128 bound)
  #pragma unroll 4
  for (int s = 0; s < 8; ++s) {
    s16x8 bfrag[4];
    #pragma unroll
    for (int nt = 0; nt < 4; ++nt) {
      uint4 raw = Bp4[(s * 32 + (w * 4 + nt)) * 64 + lane];   // L2-resident, 16 B/lane
      bfrag[nt] = __builtin_bit_cast(s16x8, raw);
    }
    s16x8 afrag[2];
    #pragma unroll
    for (int mt = 0; mt < 2; ++mt) {
      int base = (mt * 16 + l15) * LDA + s * 32 + q * 8;
      float4 a0 = *(const float4*)&As[base];       // ds_read_b128
      float4 a1 = *(const float4*)&As[base + 4];   // ds_read_b128
      union { unsigned u[4]; s16x8 v; } pk;
      pk.u[0] = f2bf(a0.x) | (f2bf(a0.y) << 16);
      pk.u[1] = f2bf(a0.z) | (f2bf(a0.w) << 16);
      pk.u[2] = f2bf(a1.x) | (f2bf(a1.y) << 16);
      pk.u[3] = f2bf(a1.z) | (f2bf(a1.w) << 16);
      afrag[mt] = pk.v;
    }
    #pragma unroll
    for (int mt = 0; mt < 2; ++mt)
      #pragma unroll
      for (int nt = 0; nt < 4; ++nt)
        acc[mt][nt] = __builtin_amdgcn_mfma_f32_16x16x32_bf16(
            afrag[mt], bfrag[nt], acc[mt][nt], 0, 0, 0);
  }

  // ReLU + per-row sum/sumsq (shuffle over the 16 col-lanes, LDS across waves)
  // C/D layout: row = q*4 + reg (+16*mt), col = l15 (+16*nt + 64*w)
  #pragma unroll
  for (int mt = 0; mt < 2; ++mt) {
    #pragma unroll
    for (int v = 0; v < 4; ++v) {
      float ss = 0.f, sq = 0.f;
      #pragma unroll
      for (int nt = 0; nt < 4; ++nt) {
        float val = fmaxf(acc[mt][nt][v], 0.f);
        acc[mt][nt][v] = val;
        ss += val;
        sq += val * val;
      }
      #pragma unroll
      for (int off = 1; off < 16; off <<= 1) {
        ss += __shfl_xor(ss, off);
        sq += __shfl_xor(sq, off);
      }
      if (l15 == 0) {
        int r = mt * 16 + q * 4 + v;
        redS[w * BM + r] = ss;
        redQ[w * BM + r] = sq;
      }
    }
  }
  __syncthreads();   // also: last As read is done -> Os may overwrite smem after this
  if (tid < BM) {
    float S = 0.f, Q = 0.f;
    #pragma unroll
    for (int ww = 0; ww < 8; ++ww) { S += redS[ww * BM + tid]; Q += redQ[ww * BM + tid]; }
    float mu  = S * (1.f / 512.f);
    float var = Q * (1.f / 512.f) - mu * mu;   // biased variance (torch default)
    statM[tid] = mu;
    statR[tid] = rsqrtf(var + 1e-5f);
  }
  __syncthreads();

  // LN -> LDS out-tile (row stride LDO=516: q-groups land 2-way max -> conflict-free)
  #pragma unroll
  for (int mt = 0; mt < 2; ++mt) {
    #pragma unroll
    for (int v = 0; v < 4; ++v) {
      int r = mt * 16 + q * 4 + v;
      float mu = statM[r], rs = statR[r];
      #pragma unroll
      for (int nt = 0; nt < 4; ++nt) {
        Os[r * LDO + w * 64 + nt * 16 + l15] =
            (acc[mt][nt][v] - mu) * rs * gv[nt] + bv[nt];
      }
    }
  }
  __syncthreads();

  // coalesced copy-out: 4096 float4 per block, 16 B/lane, 1 KiB contiguous per wave,
  // nontemporal (write-once stream, skip L2)
  #pragma unroll
  for (int it = 0; it < 8; ++it) {
    int idx = it * 512 + tid;          // 0..4095
    int r   = idx >> 7;                // 128 float4 per row
    int c4  = idx & 127;
    f32x4 val = *(const f32x4*)&Os[r * LDO + c4 * 4];
    __builtin_nontemporal_store(val,
        (f32x4*)&out[(rowbase + r) * (long)N_DIM + c4 * 4]);
  }
}

extern "C" void kernel_launch(void* const* d_in, const int* in_sizes, int n_in,
                              void* d_out, int out_size, void* d_ws, size_t ws_size,
                              hipStream_t stream) {
  const float* x     = (const float*)d_in[0];
  // d_in[1] = W_q, d_in[2] = W_k : provably unused (softmax-sum identity)
  const float* Wv    = (const float*)d_in[3];
  const float* Wr    = (const float*)d_in[4];
  const float* mix   = (const float*)d_in[5];
  const float* gamma = (const float*)d_in[6];
  const float* beta  = (const float*)d_in[7];
  float* out = (float*)d_out;
  unsigned short* Bp = (unsigned short*)d_ws;   // 256 KiB packed W_mix

  prep_wmix<<<131072 / 256, 256, 0, stream>>>(Wv, Wr, mix, Bp);
  gemm_ln<<<ROWS_TOT / BM, 512, 0, stream>>>(x, Bp, gamma, beta, out);
}

// Round 3
// 392.135 us; speedup vs baseline: 1.0224x; 1.0224x over previous
//
#include <hip/hip_runtime.h>

// AttnInteractionLayer reduces algebraically to:
//   out = LN(ReLU(x @ (m*W_v + (1-m)*W_r))) * gamma + beta,  m = sigmoid(mix[0])
// (softmax summed over its own axis == 1 -> attention pair is vals-identity; W_q,W_k dead.)
// Kernel 1: pack W_mix -> bf16 in MFMA B-fragment order (256 KiB in d_ws).
// Kernel 2: fused GEMM + ReLU + LayerNorm. A is converted fp32->bf16 ONCE at staging
//           (register path), stored in LDS in fragment-friendly bf16 layout; K-loop is
//           pure ds_read_b128 + MFMA (no per-step conversion VALU).

#define ROWS_TOT 131072   // 2048*64
#define K_DIM 256
#define N_DIM 512
#define BM 32
#define LDAB 264          // bf16 row stride in LDS: 264*2B=528B -> 4-bank rotation/row, <=2-way

typedef float f32x4 __attribute__((ext_vector_type(4)));
typedef short s16x8 __attribute__((ext_vector_type(8)));

__device__ __forceinline__ unsigned f2bf(float f) {
  unsigned u = __builtin_bit_cast(unsigned, f);
  u += 0x7FFFu + ((u >> 16) & 1u);   // round-to-nearest-even
  return u >> 16;
}

// ---- Kernel 1: W_mix = m*W_v + (1-m)*W_r, packed per 16x16x32 B-fragment layout:
//   B[k][n] -> tile (ks=k/32, nt=n/16), lane = (k%32/8)*16 + n%16, j = k%8
__global__ void prep_wmix(const float* __restrict__ Wv, const float* __restrict__ Wr,
                          const float* __restrict__ mix, unsigned short* __restrict__ Bp) {
  int idx = blockIdx.x * 256 + threadIdx.x;   // 0..131071 ; idx = k*512 + n
  float m = 1.f / (1.f + __expf(-mix[0]));
  float val = m * Wv[idx] + (1.f - m) * Wr[idx];
  int k = idx >> 9, n = idx & 511;
  int ks = k >> 5, kin = k & 31, nt = n >> 4, nin = n & 15;
  int lane = ((kin >> 3) << 4) | nin;
  int j = kin & 7;
  Bp[((ks * 32 + nt) * 64 + lane) * 8 + j] = (unsigned short)f2bf(val);
}

// ---- Kernel 2: per block: 32 rows x 512 cols. 8 waves; wave w owns cols [64w,64w+64).
__global__ __launch_bounds__(512, 4) void gemm_ln(
    const float* __restrict__ x, const unsigned short* __restrict__ Bp,
    const float* __restrict__ gamma, const float* __restrict__ beta,
    float* __restrict__ out) {
  __shared__ unsigned short As[BM * LDAB];   // 16.9 KiB bf16 A tile, K=256 resident
  __shared__ float redS[8 * BM];
  __shared__ float redQ[8 * BM];
  __shared__ float statM[BM];
  __shared__ float statR[BM];

  const int tid  = threadIdx.x;
  const int w    = tid >> 6;
  const int lane = tid & 63;
  const int q    = lane >> 4;
  const int l15  = lane & 15;
  const long rowbase = (long)blockIdx.x * BM;

  // ---- stage A: coalesced float4 loads -> convert once -> ds_write_b64.
  // thread: row r = tid>>4, t = tid&15; load i: x[r][i*64 + t*4 .. +4)
  {
    const int r = tid >> 4, t = tid & 15;
    const float* xrow = x + (rowbase + r) * K_DIM;
    #pragma unroll
    for (int i = 0; i < 4; ++i) {
      f32x4 a = *(const f32x4*)&xrow[i * 64 + t * 4];     // wave: 4 rows x 256B contig
      unsigned p0 = f2bf(a.x) | (f2bf(a.y) << 16);
      unsigned p1 = f2bf(a.z) | (f2bf(a.w) << 16);
      unsigned* dst = (unsigned*)&As[r * LDAB + i * 64 + t * 4];
      dst[0] = p0;   // ds_write_b64: banks (4r+2t)%32, 16-lane group covers 32 banks once
      dst[1] = p1;
    }
  }

  float gv[4], bv[4];
  #pragma unroll
  for (int nt = 0; nt < 4; ++nt) {
    int col = w * 64 + nt * 16 + l15;
    gv[nt] = gamma[col];
    bv[nt] = beta[col];
  }

  __syncthreads();

  f32x4 acc[2][4] = {};
  const uint4* Bp4 = (const uint4*)Bp;

  // barrier-free K-loop: 8 K-steps of 32; A-frag = one ds_read_b128 (8 bf16 exact)
  #pragma unroll 2
  for (int s = 0; s < 8; ++s) {
    s16x8 bfrag[4];
    #pragma unroll
    for (int nt = 0; nt < 4; ++nt) {
      uint4 raw = Bp4[(s * 32 + (w * 4 + nt)) * 64 + lane];   // L2-resident, 16 B/lane
      bfrag[nt] = __builtin_bit_cast(s16x8, raw);
    }
    s16x8 afrag[2];
    #pragma unroll
    for (int mt = 0; mt < 2; ++mt) {
      // lane -> A[m = l15 + 16*mt][k = s*32 + q*8 .. +8): contiguous 16 B
      afrag[mt] = *(const s16x8*)&As[(mt * 16 + l15) * LDAB + s * 32 + q * 8];
    }
    #pragma unroll
    for (int mt = 0; mt < 2; ++mt)
      #pragma unroll
      for (int nt = 0; nt < 4; ++nt)
        acc[mt][nt] = __builtin_amdgcn_mfma_f32_16x16x32_bf16(
            afrag[mt], bfrag[nt], acc[mt][nt], 0, 0, 0);
  }

  // ReLU + per-row sum/sumsq (shuffle over the 16 col-lanes, LDS across waves)
  // C/D layout: row = q*4 + reg (+16*mt), col = l15 (+16*nt + 64*w)
  #pragma unroll
  for (int mt = 0; mt < 2; ++mt) {
    #pragma unroll
    for (int v = 0; v < 4; ++v) {
      float ss = 0.f, sq = 0.f;
      #pragma unroll
      for (int nt = 0; nt < 4; ++nt) {
        float val = fmaxf(acc[mt][nt][v], 0.f);
        acc[mt][nt][v] = val;
        ss += val;
        sq += val * val;
      }
      #pragma unroll
      for (int off = 1; off < 16; off <<= 1) {
        ss += __shfl_xor(ss, off);
        sq += __shfl_xor(sq, off);
      }
      if (l15 == 0) {
        int r = mt * 16 + q * 4 + v;
        redS[w * BM + r] = ss;
        redQ[w * BM + r] = sq;
      }
    }
  }
  __syncthreads();
  if (tid < BM) {
    float S = 0.f, Q = 0.f;
    #pragma unroll
    for (int ww = 0; ww < 8; ++ww) { S += redS[ww * BM + tid]; Q += redQ[ww * BM + tid]; }
    float mu  = S * (1.f / 512.f);
    float var = Q * (1.f / 512.f) - mu * mu;   // biased variance (torch default)
    statM[tid] = mu;
    statR[tid] = rsqrtf(var + 1e-5f);
  }
  __syncthreads();

  // LN + direct stores (proven equivalent to staged-coalesced in R2)
  #pragma unroll
  for (int mt = 0; mt < 2; ++mt) {
    #pragma unroll
    for (int v = 0; v < 4; ++v) {
      int r = mt * 16 + q * 4 + v;
      float mu = statM[r], rs = statR[r];
      #pragma unroll
      for (int nt = 0; nt < 4; ++nt) {
        out[(rowbase + r) * (long)N_DIM + w * 64 + nt * 16 + l15] =
            (acc[mt][nt][v] - mu) * rs * gv[nt] + bv[nt];
      }
    }
  }
}

extern "C" void kernel_launch(void* const* d_in, const int* in_sizes, int n_in,
                              void* d_out, int out_size, void* d_ws, size_t ws_size,
                              hipStream_t stream) {
  const float* x     = (const float*)d_in[0];
  // d_in[1] = W_q, d_in[2] = W_k : provably unused (softmax-sum identity)
  const float* Wv    = (const float*)d_in[3];
  const float* Wr    = (const float*)d_in[4];
  const float* mix   = (const float*)d_in[5];
  const float* gamma = (const float*)d_in[6];
  const float* beta  = (const float*)d_in[7];
  float* out = (float*)d_out;
  unsigned short* Bp = (unsigned short*)d_ws;   // 256 KiB packed W_mix

  prep_wmix<<<131072 / 256, 256, 0, stream>>>(Wv, Wr, mix, Bp);
  gemm_ln<<<ROWS_TOT / BM, 512, 0, stream>>>(x, Bp, gamma, beta, out);
}